// Round 6
// baseline (447.104 us; speedup 1.0000x reference)
//
#include <hip/hip_runtime.h>
#include <cstdint>
#include <cstddef>

#define NEG_SLOPE 0.2f

// ---------------------------------------------------------------------------
// CSR build: count -> scan (3 kernels) -> bin -> local fill
// ---------------------------------------------------------------------------
__global__ void count_edges(const int* __restrict__ ei, int* __restrict__ cnt,
                            int E, int total) {
    int e = blockIdx.x * blockDim.x + threadIdx.x;
    if (e >= total) return;
    int dst = (e < E) ? ei[E + e] : (e - E);   // self-loops appended
    atomicAdd(&cnt[dst], 1);
}

__global__ void scan1(const int* __restrict__ cnt, int* __restrict__ part, int n) {
    __shared__ int red[256];
    int base = blockIdx.x * 1024;
    int s = 0;
    for (int i = threadIdx.x; i < 1024; i += 256) {
        int idx = base + i;
        s += (idx < n) ? cnt[idx] : 0;
    }
    red[threadIdx.x] = s;
    __syncthreads();
    for (int off = 128; off; off >>= 1) {
        if (threadIdx.x < off) red[threadIdx.x] += red[threadIdx.x + off];
        __syncthreads();
    }
    if (threadIdx.x == 0) part[blockIdx.x] = red[0];
}

// single block: exclusive scan of partials (nb <= 256); also writes rp[n]=total
__global__ void scan2(int* __restrict__ part, int nb, int* __restrict__ rp, int n) {
    __shared__ int sc[256];
    int t = threadIdx.x;
    int v = (t < nb) ? part[t] : 0;
    sc[t] = v;
    __syncthreads();
    for (int off = 1; off < 256; off <<= 1) {
        int x = (t >= off) ? sc[t - off] : 0;
        __syncthreads();
        sc[t] += x;
        __syncthreads();
    }
    if (t < nb) part[t] = sc[t] - v;        // exclusive
    if (t == 255) rp[n] = sc[255];          // total edge count
}

__global__ void scan3(const int* __restrict__ cnt, const int* __restrict__ part,
                      int* __restrict__ rp, int n) {
    __shared__ int tsum[256];
    int base = blockIdx.x * 1024;
    int t = threadIdx.x;
    int v[4];
    int loc = 0;
#pragma unroll
    for (int i = 0; i < 4; ++i) {
        int idx = base + t * 4 + i;
        v[i] = (idx < n) ? cnt[idx] : 0;
        loc += v[i];
    }
    tsum[t] = loc;
    __syncthreads();
    for (int off = 1; off < 256; off <<= 1) {
        int x = (t >= off) ? tsum[t - off] : 0;
        __syncthreads();
        tsum[t] += x;
        __syncthreads();
    }
    int excl = tsum[t] - loc + part[blockIdx.x];
#pragma unroll
    for (int i = 0; i < 4; ++i) {
        int idx = base + t * 4 + i;
        if (idx < n) rp[idx] = excl;
        excl += v[i];
    }
}

// bucket cursors = CSR offset of each bucket's first node (bucket = 512 nodes)
__global__ void bcur_init(const int* __restrict__ rp, int* __restrict__ bcur,
                          int n, int nb) {
    int t = threadIdx.x;
    if (t < nb) bcur[t] = rp[min(t * 512, n)];
    else if (t < 256) bcur[t] = 0;
}

// ---------------------------------------------------------------------------
// Pass 1: bin edges into 512-node coarse buckets.
// ---------------------------------------------------------------------------
#define BIN_K 16   // edges per thread; chunk = 256*16 = 4096
__global__ __launch_bounds__(256) void bin_edges(
    const int* __restrict__ ei, int* __restrict__ bcur,
    int2* __restrict__ ebuf, int E, int total) {
    __shared__ int lhist[256];
    __shared__ int lbase[256];
    int tid = threadIdx.x;
    lhist[tid] = 0;
    __syncthreads();
    int base_e = blockIdx.x * (256 * BIN_K);
    int s[BIN_K], d[BIN_K], bk[BIN_K];
#pragma unroll
    for (int k = 0; k < BIN_K; ++k) {
        int e = base_e + tid + k * 256;
        bool v = e < total;
        int ee = v ? e : 0;
        if (ee < E) { s[k] = ei[ee]; d[k] = ei[E + ee]; }
        else        { s[k] = d[k] = ee - E; }
        bk[k] = v ? (d[k] >> 9) : -1;
        if (v) atomicAdd(&lhist[bk[k]], 1);
    }
    __syncthreads();
    int h = lhist[tid];
    lbase[tid] = (h > 0) ? atomicAdd(&bcur[tid], h) : 0;
    __syncthreads();
    lhist[tid] = 0;
    __syncthreads();
#pragma unroll
    for (int k = 0; k < BIN_K; ++k) {
        if (bk[k] >= 0) {
            int r = atomicAdd(&lhist[bk[k]], 1);
            ebuf[(size_t)lbase[bk[k]] + r] = make_int2(s[k], d[k]);
        }
    }
}

// ---------------------------------------------------------------------------
// Pass 2: one block per bucket; node cursors in LDS, writes stay local.
// ---------------------------------------------------------------------------
__global__ __launch_bounds__(256) void local_fill(
    const int2* __restrict__ ebuf, const int* __restrict__ rp,
    int* __restrict__ cs, int n) {
    __shared__ int lcur[512];
    int node0 = blockIdx.x * 512;
    int nodes = min(512, n - node0);
    int tid = threadIdx.x;
    for (int j = tid; j < nodes; j += 256) lcur[j] = rp[node0 + j];
    __syncthreads();
    int beg = rp[node0];
    int end = rp[node0 + nodes];
    for (int base = beg; base < end; base += 256 * 8) {
        int2 pr[8];
        int idx[8];
#pragma unroll
        for (int u = 0; u < 8; ++u) {
            idx[u] = base + tid + u * 256;
            pr[u] = ebuf[(idx[u] < end) ? idx[u] : beg];
        }
#pragma unroll
        for (int u = 0; u < 8; ++u) {
            if (idx[u] < end) {
                int pos = atomicAdd(&lcur[pr[u].y - node0], 1);
                cs[pos] = pr[u].x;
            }
        }
    }
}

// ---------------------------------------------------------------------------
// Precompute Was = W @ a_s, Wad = W @ a_d for layers 2 and 3 (1 block, 64 thr)
// ---------------------------------------------------------------------------
__global__ void wa_prep(const float* __restrict__ W2, const float* __restrict__ as2,
                        const float* __restrict__ ad2,
                        const float* __restrict__ W3, const float* __restrict__ as3,
                        const float* __restrict__ ad3,
                        float* __restrict__ Was2, float* __restrict__ Wad2,
                        float* __restrict__ Was3, float* __restrict__ Wad3) {
    int k = threadIdx.x;            // 0..63
    float s2 = 0.f, d2 = 0.f, s3 = 0.f, d3 = 0.f;
    for (int j = 0; j < 64; ++j) {
        float w = W2[k * 64 + j];
        s2 = fmaf(w, as2[j], s2);
        d2 = fmaf(w, ad2[j], d2);
    }
    for (int j = 0; j < 32; ++j) {
        float w = W3[k * 32 + j];
        s3 = fmaf(w, as3[j], s3);
        d3 = fmaf(w, ad3[j], d3);
    }
    Was2[k] = s2; Wad2[k] = d2; Was3[k] = s3; Wad3[k] = d3;
}

// ---------------------------------------------------------------------------
// Fused projection + attention dots:  h = x @ W ; hs = h@a_s ; hd = h@a_d
// (layer 1 only; layers 2/3 projections are fused into aggregate_fused)
// ---------------------------------------------------------------------------
template <int INF, int OUTF>
__global__ void gemm_attn(const float* __restrict__ x, const float* __restrict__ W,
                          const float* __restrict__ a_s, const float* __restrict__ a_d,
                          float* __restrict__ h, float* __restrict__ hs,
                          float* __restrict__ hd, int n) {
    constexpr int FC  = OUTF / 4;          // threads along feature dim
    constexpr int NPB = 64;                // nodes per block
    constexpr int NT  = FC * (NPB / 4);    // threads per block
    __shared__ float Wl[INF * OUTF];
    int tid = threadIdx.x;
    for (int i = tid; i < INF * OUTF; i += NT) Wl[i] = W[i];
    __syncthreads();

    int fc = tid % FC;
    int nc = tid / FC;                     // 0..15
    int n0 = blockIdx.x * NPB + nc * 4;
    int ni[4];
#pragma unroll
    for (int i = 0; i < 4; ++i) { int v = n0 + i; ni[i] = (v < n) ? v : (n - 1); }

    float acc[4][4] = {};
#pragma unroll 2
    for (int k = 0; k < INF; k += 4) {
        float4 xv[4];
#pragma unroll
        for (int i = 0; i < 4; ++i)
            xv[i] = *reinterpret_cast<const float4*>(&x[(size_t)ni[i] * INF + k]);
#pragma unroll
        for (int j = 0; j < 4; ++j) {
            float4 wv = *reinterpret_cast<const float4*>(&Wl[(k + j) * OUTF + fc * 4]);
#pragma unroll
            for (int i = 0; i < 4; ++i) {
                float xs = (&xv[i].x)[j];
                acc[i][0] = fmaf(xs, wv.x, acc[i][0]);
                acc[i][1] = fmaf(xs, wv.y, acc[i][1]);
                acc[i][2] = fmaf(xs, wv.z, acc[i][2]);
                acc[i][3] = fmaf(xs, wv.w, acc[i][3]);
            }
        }
    }

    float asv[4], adv[4];
#pragma unroll
    for (int j = 0; j < 4; ++j) { asv[j] = a_s[fc * 4 + j]; adv[j] = a_d[fc * 4 + j]; }

#pragma unroll
    for (int i = 0; i < 4; ++i) {
        float ps = acc[i][0] * asv[0] + acc[i][1] * asv[1] +
                   acc[i][2] * asv[2] + acc[i][3] * asv[3];
        float pd = acc[i][0] * adv[0] + acc[i][1] * adv[1] +
                   acc[i][2] * adv[2] + acc[i][3] * adv[3];
#pragma unroll
        for (int off = FC >> 1; off; off >>= 1) {
            ps += __shfl_xor(ps, off, FC);
            pd += __shfl_xor(pd, off, FC);
        }
        int node = n0 + i;
        if (node < n) {
            *reinterpret_cast<float4*>(&h[(size_t)node * OUTF + fc * 4]) =
                make_float4(acc[i][0], acc[i][1], acc[i][2], acc[i][3]);
            if (fc == 0) { hs[node] = ps; hd[node] = pd; }
        }
    }
}

// ---------------------------------------------------------------------------
// Fused: wave-cooperative online-softmax aggregation (F=64, 1 node/wave,
// 2-edge-parallel float2 gathers, first 12 pair-gathers HOISTED above the
// softmax so their L3 latency overlaps the shuffle-reduce chain)
// + next-layer projection epilogue:
//   row = relu(agg + b);  hn = row @ W;  hsn = row.Was;  hdn = row.Wad
// ---------------------------------------------------------------------------
template <int NEXT>
__global__ __launch_bounds__(256) void aggregate_fused(
    const float* __restrict__ h, const float* __restrict__ hs,
    const float* __restrict__ hd, const int* __restrict__ rp,
    const int* __restrict__ cs, const float* __restrict__ b,
    const float* __restrict__ W,                                   // 64 x NEXT
    const float* __restrict__ Was, const float* __restrict__ Wad,  // 64
    float* __restrict__ hn, float* __restrict__ hsn, float* __restrict__ hdn_o,
    int n) {
    constexpr int F = 64, HF = 32, P = 12;   // deg<=24 fully covered by hoist
    __shared__ float Wl[64 * NEXT];
    __shared__ float WasL[64], WadL[64];
    __shared__ float rowbuf[4][64];
    int tid = threadIdx.x;
    for (int i = tid; i < 64 * NEXT; i += 256) Wl[i] = W[i];
    if (tid < 64) { WasL[tid] = Was[tid]; WadL[tid] = Wad[tid]; }
    __syncthreads();

    int wid  = (blockIdx.x * blockDim.x + tid) >> 6;
    int lane = tid & 63;
    int wb   = tid >> 6;
    if (wid >= n) return;
    int node = wid;
    int beg = rp[node], end = rp[node + 1];
    float hdn = hd[node];
    int half = lane >> 5;                  // which edge of each pair
    int f2   = (lane & 31) * 2;            // feature-pair base
    float2 bb2 = *reinterpret_cast<const float2*>(&b[f2]);

    float m = -1e30f, s = 0.f;
    float2 acc = make_float2(0.f, 0.f);

    for (int base = beg; base < end; base += F) {
        int e = base + lane;
        bool v = e < end;
        int src = cs[v ? e : beg];

        // hoisted pair gathers (independent of softmax)
        float2 hp[P];
#pragma unroll
        for (int u = 0; u < P; ++u) {
            int se = __shfl(src, 2 * u + half, F);
            hp[u] = *reinterpret_cast<const float2*>(&h[(size_t)se * 64 + f2]);
        }

        // lane-parallel logits + wave softmax
        float l = hs[src] + hdn;
        l = (l > 0.f) ? l : NEG_SLOPE * l;
        l = v ? l : -1e30f;
        float lm = l;
#pragma unroll
        for (int off = HF; off; off >>= 1)
            lm = fmaxf(lm, __shfl_xor(lm, off, F));
        float mn = fmaxf(m, lm);
        float w = __expf(l - mn);          // exactly 0 for padded lanes
        float ws = w;
#pragma unroll
        for (int off = HF; off; off >>= 1)
            ws += __shfl_xor(ws, off, F);
        float sc = __expf(m - mn);
        s = fmaf(s, sc, ws);
        acc.x *= sc; acc.y *= sc;
        m = mn;

        // accumulate hoisted pairs (w of padded edges is 0)
#pragma unroll
        for (int u = 0; u < P; ++u) {
            float we = __shfl(w, 2 * u + half, F);
            acc.x = fmaf(we, hp[u].x, acc.x);
            acc.y = fmaf(we, hp[u].y, acc.y);
        }

        // remainder pairs (deg > 2P), batched x4 with predicates
        int cc = min(F, end - base);
        for (int t = P; 2 * t < cc; t += 4) {
            float2 hv[4];
            float  wv[4];
#pragma unroll
            for (int u = 0; u < 4; ++u) {
                int tt = t + u;
                bool pv = (2 * tt < cc);
                int jj = pv ? (2 * tt + half) : 0;
                int   se = __shfl(src, jj, F);
                float we = __shfl(w,   jj, F);
                wv[u] = pv ? we : 0.f;
                hv[u] = *reinterpret_cast<const float2*>(&h[(size_t)se * 64 + f2]);
            }
#pragma unroll
            for (int u = 0; u < 4; ++u) {
                acc.x = fmaf(wv[u], hv[u].x, acc.x);
                acc.y = fmaf(wv[u], hv[u].y, acc.y);
            }
        }
    }

    // merge the two edge-stream halves; every lane then holds its full pair
    acc.x += __shfl_xor(acc.x, HF, F);
    acc.y += __shfl_xor(acc.y, HF, F);

    float inv = 1.f / (s + 1e-16f);
    float2 res;
    res.x = fmaxf(fmaf(acc.x, inv, bb2.x), 0.f);
    res.y = fmaxf(fmaf(acc.y, inv, bb2.y), 0.f);

    // ---- epilogue: project row -> next layer ----
    if (half == 0) { rowbuf[wb][f2] = res.x; rowbuf[wb][f2 + 1] = res.y; }
    // same-wave LDS RAW: compiler inserts the lgkmcnt wait; no barrier needed.

    // hsn/hdn via precomputed Was/Wad: (row@W).a == row.(W@a)
    float ps = (half == 0) ? (res.x * WasL[f2] + res.y * WasL[f2 + 1]) : 0.f;
    float pd = (half == 0) ? (res.x * WadL[f2] + res.y * WadL[f2 + 1]) : 0.f;
#pragma unroll
    for (int off = HF; off; off >>= 1) {
        ps += __shfl_xor(ps, off, F);
        pd += __shfl_xor(pd, off, F);
    }
    if (lane == 0) { hsn[node] = ps; hdn_o[node] = pd; }

    if (NEXT == 64) {
        float hacc = 0.f;
#pragma unroll
        for (int k = 0; k < 64; k += 2) {
            float2 r = *reinterpret_cast<const float2*>(&rowbuf[wb][k]);
            hacc = fmaf(r.x, Wl[k * 64 + lane], hacc);
            hacc = fmaf(r.y, Wl[(k + 1) * 64 + lane], hacc);
        }
        hn[(size_t)node * 64 + lane] = hacc;
    } else {   // NEXT == 32: halves split the k-range, then merge
        int j  = lane & 31;
        int k0 = half * 32;
        float hacc = 0.f;
#pragma unroll
        for (int k = 0; k < 32; k += 2) {
            float2 r = *reinterpret_cast<const float2*>(&rowbuf[wb][k0 + k]);
            hacc = fmaf(r.x, Wl[(k0 + k) * NEXT + j], hacc);
            hacc = fmaf(r.y, Wl[(k0 + k + 1) * NEXT + j], hacc);
        }
        hacc += __shfl_xor(hacc, HF, F);
        if (half == 0) hn[(size_t)node * 32 + j] = hacc;
    }
}

// ---------------------------------------------------------------------------
// Plain wave-cooperative aggregation for the last layer (F=32, 2 nodes/wave)
// ---------------------------------------------------------------------------
template <int F>
__global__ __launch_bounds__(256) void aggregate(
    const float* __restrict__ h, const float* __restrict__ hs,
    const float* __restrict__ hd, const int* __restrict__ rp,
    const int* __restrict__ cs, const float* __restrict__ b,
    float* __restrict__ out, int n) {
    constexpr int NPW = 64 / F;            // nodes per wave
    constexpr int HF  = F / 2;
    int wid  = (blockIdx.x * blockDim.x + threadIdx.x) >> 6;
    int lane = threadIdx.x & 63;
    int fl   = lane % F;
    int node = wid * NPW + lane / F;
    if (node >= n) return;
    int beg = rp[node], end = rp[node + 1];
    float hdn = hd[node];

    int half = (fl >= HF) ? 1 : 0;
    int f2   = (fl & (HF - 1)) * 2;
    float2 bb2 = *reinterpret_cast<const float2*>(&b[f2]);

    float m = -1e30f, s = 0.f;
    float2 acc = make_float2(0.f, 0.f);

    for (int base = beg; base < end; base += F) {
        int e = base + fl;
        bool v = e < end;
        int src = cs[v ? e : beg];
        float l = hs[src] + hdn;
        l = (l > 0.f) ? l : NEG_SLOPE * l;
        l = v ? l : -1e30f;
        float lm = l;
#pragma unroll
        for (int off = HF; off; off >>= 1)
            lm = fmaxf(lm, __shfl_xor(lm, off, F));
        float mn = fmaxf(m, lm);
        float w = __expf(l - mn);
        float ws = w;
#pragma unroll
        for (int off = HF; off; off >>= 1)
            ws += __shfl_xor(ws, off, F);
        float sc = __expf(m - mn);
        s = fmaf(s, sc, ws);
        acc.x *= sc; acc.y *= sc;
        m = mn;

        int cc = min(F, end - base);
        for (int t = 0; 2 * t < cc; t += 4) {
            float2 hv[4];
            float  wv[4];
#pragma unroll
            for (int u = 0; u < 4; ++u) {
                int tt = t + u;
                bool pv = (2 * tt < cc);
                int jj = pv ? (2 * tt + half) : 0;
                int   se = __shfl(src, jj, F);
                float we = __shfl(w,   jj, F);
                wv[u] = pv ? we : 0.f;
                hv[u] = *reinterpret_cast<const float2*>(&h[(size_t)se * F + f2]);
            }
#pragma unroll
            for (int u = 0; u < 4; ++u) {
                acc.x = fmaf(wv[u], hv[u].x, acc.x);
                acc.y = fmaf(wv[u], hv[u].y, acc.y);
            }
        }
    }

    acc.x += __shfl_xor(acc.x, HF, F);
    acc.y += __shfl_xor(acc.y, HF, F);

    float inv = 1.f / (s + 1e-16f);
    float2 res;
    res.x = fmaxf(fmaf(acc.x, inv, bb2.x), 0.f);
    res.y = fmaxf(fmaf(acc.y, inv, bb2.y), 0.f);
    if (half == 0)
        *reinterpret_cast<float2*>(&out[(size_t)node * F + f2]) = res;
}

// ---------------------------------------------------------------------------
// Global mean pool (batch is sorted): LDS pre-reduction then global atomics
// ---------------------------------------------------------------------------
__global__ void pool_kernel(const float* __restrict__ x, const int* __restrict__ batch,
                            float* __restrict__ pool, float* __restrict__ gcnt, int n) {
    __shared__ float lp[64 * 32];
    __shared__ float lc[64];
    int tid = threadIdx.x;
    for (int i = tid; i < 64 * 32; i += 256) lp[i] = 0.f;
    if (tid < 64) lc[tid] = 0.f;
    __syncthreads();
    int f = tid % 32, r = tid / 32;
    int base = blockIdx.x * 64;
    for (int i = r; i < 64; i += 8) {
        int node = base + i;
        if (node < n) {
            int g = batch[node];
            atomicAdd(&lp[g * 32 + f], x[(size_t)node * 32 + f]);
            if (f == 0) atomicAdd(&lc[g], 1.f);
        }
    }
    __syncthreads();
    for (int i = tid; i < 64 * 32; i += 256)
        if (lp[i] != 0.f) atomicAdd(&pool[i], lp[i]);
    if (tid < 64 && lc[tid] != 0.f) atomicAdd(&gcnt[tid], lc[tid]);
}

__global__ void finalize(const float* __restrict__ pool, const float* __restrict__ gcnt,
                         float* __restrict__ out, int total) {
    int i = blockIdx.x * blockDim.x + threadIdx.x;
    if (i >= total) return;
    out[i] = pool[i] / fmaxf(gcnt[i / 32], 1.f);
}

// ---------------------------------------------------------------------------
extern "C" void kernel_launch(void* const* d_in, const int* in_sizes, int n_in,
                              void* d_out, int out_size, void* d_ws, size_t ws_size,
                              hipStream_t stream) {
    const float* x    = (const float*)d_in[0];
    const int*   ei   = (const int*)d_in[1];
    const int*   batch= (const int*)d_in[2];
    const float* W1   = (const float*)d_in[3];
    const float* as1  = (const float*)d_in[4];
    const float* ad1  = (const float*)d_in[5];
    const float* b1   = (const float*)d_in[6];
    const float* W2   = (const float*)d_in[7];
    const float* as2  = (const float*)d_in[8];
    const float* ad2  = (const float*)d_in[9];
    const float* b2   = (const float*)d_in[10];
    const float* W3   = (const float*)d_in[11];
    const float* as3  = (const float*)d_in[12];
    const float* ad3  = (const float*)d_in[13];
    const float* b3   = (const float*)d_in[14];
    float* out = (float*)d_out;

    const int N  = in_sizes[0] / 128;
    const int E  = in_sizes[1] / 2;
    const int ET = E + N;
    const int G  = 64;
    const int NB = (N + 511) / 512;        // coarse buckets (512 nodes each)

    char* p = (char*)d_ws;
    auto alloc = [&](size_t bytes) {
        char* r = p;
        p += (bytes + 255) & ~(size_t)255;
        return r;
    };
    int*   cnt    = (int*)alloc((size_t)N * 4);
    int*   rp     = (int*)alloc((size_t)(N + 1) * 4);
    int*   part   = (int*)alloc(1024);
    int*   bcur   = (int*)alloc(1024);
    int*   cs     = (int*)alloc((size_t)ET * 4);
    float* hA     = (float*)alloc((size_t)N * 64 * 4);   // layer-1 h / layer-3 h
    float* hB     = (float*)alloc((size_t)N * 64 * 4);   // layer-2 h / agg3 out
    float* hs     = (float*)alloc((size_t)N * 4);
    float* hd     = (float*)alloc((size_t)N * 4);
    float* hs2    = (float*)alloc((size_t)N * 4);
    float* hd2    = (float*)alloc((size_t)N * 4);
    float* pool   = (float*)alloc((size_t)G * 32 * 4);
    float* gcnt   = (float*)alloc((size_t)G * 4);
    float* Was2   = (float*)alloc(256);
    float* Wad2   = (float*)alloc(256);
    float* Was3   = (float*)alloc(256);
    float* Wad3   = (float*)alloc(256);
    // ebuf aliases hB: local_fill (last reader) completes before aggf1 writes hB.
    int2*  ebuf   = (int2*)hB;

    // ---- CSR by destination (shared across all 3 layers) ----
    hipMemsetAsync(cnt, 0, (size_t)N * 4, stream);
    int eb = (ET + 255) / 256;
    count_edges<<<eb, 256, 0, stream>>>(ei, cnt, E, ET);
    int nb = (N + 1023) / 1024;
    scan1<<<nb, 256, 0, stream>>>(cnt, part, N);
    scan2<<<1, 256, 0, stream>>>(part, nb, rp, N);
    scan3<<<nb, 256, 0, stream>>>(cnt, part, rp, N);
    bcur_init<<<1, 256, 0, stream>>>(rp, bcur, N, NB);
    int bb = (ET + 256 * BIN_K - 1) / (256 * BIN_K);
    bin_edges<<<bb, 256, 0, stream>>>(ei, bcur, ebuf, E, ET);
    local_fill<<<NB, 256, 0, stream>>>(ebuf, rp, cs, N);
    wa_prep<<<1, 64, 0, stream>>>(W2, as2, ad2, W3, as3, ad3,
                                  Was2, Wad2, Was3, Wad3);

    int gb   = (N + 63) / 64;
    int ab64 = (N + 3) / 4;        // 4 waves/block, 1 node/wave
    int ab32 = (N + 7) / 8;        // 4 waves/block, 2 nodes/wave

    // ---- layer 1 projection: 128 -> 64 (x, W1 -> hA, hs, hd) ----
    gemm_attn<128, 64><<<gb, 256, 0, stream>>>(x, W1, as1, ad1, hA, hs, hd, N);
    // ---- layer-1 aggregate + layer-2 projection: hA -> hB (h2), hs2, hd2 ----
    aggregate_fused<64><<<ab64, 256, 0, stream>>>(hA, hs, hd, rp, cs, b1,
                                                  W2, Was2, Wad2,
                                                  hB, hs2, hd2, N);
    // ---- layer-2 aggregate + layer-3 projection: hB -> hA (h3, Nx32), hs, hd ----
    aggregate_fused<32><<<ab64, 256, 0, stream>>>(hB, hs2, hd2, rp, cs, b2,
                                                  W3, Was3, Wad3,
                                                  hA, hs, hd, N);
    // ---- layer-3 aggregate (plain): hA -> hB (Nx32 activations) ----
    aggregate<32><<<ab32, 256, 0, stream>>>(hA, hs, hd, rp, cs, b3, hB, N);

    // ---- global mean pool ----
    hipMemsetAsync(pool, 0, (size_t)G * 32 * 4, stream);
    hipMemsetAsync(gcnt, 0, (size_t)G * 4, stream);
    pool_kernel<<<(N + 63) / 64, 256, 0, stream>>>(hB, batch, pool, gcnt, N);
    finalize<<<(G * 32 + 255) / 256, 256, 0, stream>>>(pool, gcnt, out, G * 32);
}

// Round 7
// 328.571 us; speedup vs baseline: 1.3608x; 1.3608x over previous
//
#include <hip/hip_runtime.h>
#include <cstdint>
#include <cstddef>

#define NEG_SLOPE 0.2f

// ---------------------------------------------------------------------------
// CSR build: bucket_count -> bucket_scan (1 block) -> bin_edges -> local_fill2
// (bucket = 512 consecutive dst nodes; per-node rp built inside each bucket)
// ---------------------------------------------------------------------------
__global__ __launch_bounds__(256) void bucket_count(
    const int* __restrict__ ei, int* __restrict__ bkcnt, int E, int total) {
    __shared__ int lh[256];
    int tid = threadIdx.x;
    lh[tid] = 0;
    __syncthreads();
    int i = blockIdx.x * (256 * 8) + tid;
#pragma unroll
    for (int k = 0; k < 8; ++k, i += 256) {
        if (i < total) {
            int dst = (i < E) ? ei[E + i] : (i - E);   // self-loops appended
            atomicAdd(&lh[dst >> 9], 1);
        }
    }
    __syncthreads();
    if (lh[tid]) atomicAdd(&bkcnt[tid], lh[tid]);
}

// 1 block: exclusive scan over nb (<=256) buckets; writes bbase, bcur, rp[n]
__global__ void bucket_scan(const int* __restrict__ bkcnt, int nb,
                            int* __restrict__ bbase, int* __restrict__ bcur,
                            int* __restrict__ rp, int n) {
    __shared__ int sc[256];
    int t = threadIdx.x;
    int v = (t < nb) ? bkcnt[t] : 0;
    sc[t] = v;
    __syncthreads();
    for (int off = 1; off < 256; off <<= 1) {
        int x = (t >= off) ? sc[t - off] : 0;
        __syncthreads();
        sc[t] += x;
        __syncthreads();
    }
    int excl = sc[t] - v;
    if (t < nb) { bbase[t] = excl; bcur[t] = excl; }
    if (t == 255) { bbase[nb] = sc[255]; rp[n] = sc[255]; }
}

// ---------------------------------------------------------------------------
// Pass 1: bin edges into 512-node coarse buckets (per-block LDS histogram,
// one global atomic per touched bucket to reserve a contiguous run).
// ---------------------------------------------------------------------------
#define BIN_K 16   // edges per thread; chunk = 256*16 = 4096
__global__ __launch_bounds__(256) void bin_edges(
    const int* __restrict__ ei, int* __restrict__ bcur,
    int2* __restrict__ ebuf, int E, int total) {
    __shared__ int lhist[256];
    __shared__ int lbase[256];
    int tid = threadIdx.x;
    lhist[tid] = 0;
    __syncthreads();
    int base_e = blockIdx.x * (256 * BIN_K);
    int s[BIN_K], d[BIN_K], bk[BIN_K];
#pragma unroll
    for (int k = 0; k < BIN_K; ++k) {
        int e = base_e + tid + k * 256;
        bool v = e < total;
        int ee = v ? e : 0;
        if (ee < E) { s[k] = ei[ee]; d[k] = ei[E + ee]; }
        else        { s[k] = d[k] = ee - E; }
        bk[k] = v ? (d[k] >> 9) : -1;
        if (v) atomicAdd(&lhist[bk[k]], 1);
    }
    __syncthreads();
    int h = lhist[tid];
    lbase[tid] = (h > 0) ? atomicAdd(&bcur[tid], h) : 0;
    __syncthreads();
    lhist[tid] = 0;
    __syncthreads();
#pragma unroll
    for (int k = 0; k < BIN_K; ++k) {
        if (bk[k] >= 0) {
            int r = atomicAdd(&lhist[bk[k]], 1);
            ebuf[(size_t)lbase[bk[k]] + r] = make_int2(s[k], d[k]);
        }
    }
}

// ---------------------------------------------------------------------------
// Pass 2: one block per bucket. Builds per-node rp (LDS histogram + scan of
// the bucket's 512 nodes) and places edges with LDS cursors. All cs writes
// confined to the bucket's window -> lines filled by one XCD.
// ---------------------------------------------------------------------------
__global__ __launch_bounds__(256) void local_fill2(
    const int2* __restrict__ ebuf, const int* __restrict__ bbase,
    int* __restrict__ rp, int* __restrict__ cs, int n) {
    __shared__ int lhist[512];
    __shared__ int lscan[256];
    __shared__ int lcur[512];
    int b = blockIdx.x;
    int node0 = b * 512;
    int nodes = min(512, n - node0);
    int tid = threadIdx.x;
    int beg = bbase[b], end = bbase[b + 1];

    lhist[tid] = 0; lhist[tid + 256] = 0;
    __syncthreads();

    // pass A: histogram by node (batched x4)
    for (int i0 = beg; i0 < end; i0 += 256 * 4) {
        int2 pr[4]; int idx[4];
#pragma unroll
        for (int u = 0; u < 4; ++u) {
            idx[u] = i0 + tid + u * 256;
            pr[u] = ebuf[(idx[u] < end) ? idx[u] : beg];
        }
#pragma unroll
        for (int u = 0; u < 4; ++u)
            if (idx[u] < end) atomicAdd(&lhist[pr[u].y - node0], 1);
    }
    __syncthreads();

    // scan 512 elements (2 per thread)
    int a0 = lhist[2 * tid], a1 = lhist[2 * tid + 1];
    int psum = a0 + a1;
    lscan[tid] = psum;
    __syncthreads();
    for (int off = 1; off < 256; off <<= 1) {
        int x = (tid >= off) ? lscan[tid - off] : 0;
        __syncthreads();
        lscan[tid] += x;
        __syncthreads();
    }
    int e0 = beg + (lscan[tid] - psum);    // node 2*tid first-edge position
    int e1 = e0 + a0;                      // node 2*tid+1 first-edge position
    if (2 * tid < nodes)     rp[node0 + 2 * tid]     = e0;
    if (2 * tid + 1 < nodes) rp[node0 + 2 * tid + 1] = e1;
    lcur[2 * tid] = e0;
    lcur[2 * tid + 1] = e1;
    __syncthreads();

    // pass B: place edges (batched x4)
    for (int i0 = beg; i0 < end; i0 += 256 * 4) {
        int2 pr[4]; int idx[4];
#pragma unroll
        for (int u = 0; u < 4; ++u) {
            idx[u] = i0 + tid + u * 256;
            pr[u] = ebuf[(idx[u] < end) ? idx[u] : beg];
        }
#pragma unroll
        for (int u = 0; u < 4; ++u) {
            if (idx[u] < end) {
                int pos = atomicAdd(&lcur[pr[u].y - node0], 1);
                cs[pos] = pr[u].x;
            }
        }
    }
}

// ---------------------------------------------------------------------------
// Fused projection + attention dots:  h = x @ W ; hs = h@a_s ; hd = h@a_d
// Register blocking: 4 nodes x 4 features per thread; W staged in LDS.
// ---------------------------------------------------------------------------
template <int INF, int OUTF>
__global__ void gemm_attn(const float* __restrict__ x, const float* __restrict__ W,
                          const float* __restrict__ a_s, const float* __restrict__ a_d,
                          float* __restrict__ h, float* __restrict__ hs,
                          float* __restrict__ hd, int n) {
    constexpr int FC  = OUTF / 4;          // threads along feature dim
    constexpr int NPB = 64;                // nodes per block
    constexpr int NT  = FC * (NPB / 4);    // threads per block
    __shared__ float Wl[INF * OUTF];
    int tid = threadIdx.x;
    for (int i = tid; i < INF * OUTF; i += NT) Wl[i] = W[i];
    __syncthreads();

    int fc = tid % FC;
    int nc = tid / FC;                     // 0..15
    int n0 = blockIdx.x * NPB + nc * 4;
    int ni[4];
#pragma unroll
    for (int i = 0; i < 4; ++i) { int v = n0 + i; ni[i] = (v < n) ? v : (n - 1); }

    float acc[4][4] = {};
#pragma unroll 2
    for (int k = 0; k < INF; k += 4) {
        float4 xv[4];
#pragma unroll
        for (int i = 0; i < 4; ++i)
            xv[i] = *reinterpret_cast<const float4*>(&x[(size_t)ni[i] * INF + k]);
#pragma unroll
        for (int j = 0; j < 4; ++j) {
            float4 wv = *reinterpret_cast<const float4*>(&Wl[(k + j) * OUTF + fc * 4]);
#pragma unroll
            for (int i = 0; i < 4; ++i) {
                float xs = (&xv[i].x)[j];
                acc[i][0] = fmaf(xs, wv.x, acc[i][0]);
                acc[i][1] = fmaf(xs, wv.y, acc[i][1]);
                acc[i][2] = fmaf(xs, wv.z, acc[i][2]);
                acc[i][3] = fmaf(xs, wv.w, acc[i][3]);
            }
        }
    }

    float asv[4], adv[4];
#pragma unroll
    for (int j = 0; j < 4; ++j) { asv[j] = a_s[fc * 4 + j]; adv[j] = a_d[fc * 4 + j]; }

#pragma unroll
    for (int i = 0; i < 4; ++i) {
        float ps = acc[i][0] * asv[0] + acc[i][1] * asv[1] +
                   acc[i][2] * asv[2] + acc[i][3] * asv[3];
        float pd = acc[i][0] * adv[0] + acc[i][1] * adv[1] +
                   acc[i][2] * adv[2] + acc[i][3] * adv[3];
#pragma unroll
        for (int off = FC >> 1; off; off >>= 1) {
            ps += __shfl_xor(ps, off, FC);
            pd += __shfl_xor(pd, off, FC);
        }
        int node = n0 + i;
        if (node < n) {
            *reinterpret_cast<float4*>(&h[(size_t)node * OUTF + fc * 4]) =
                make_float4(acc[i][0], acc[i][1], acc[i][2], acc[i][3]);
            if (fc == 0) { hs[node] = ps; hd[node] = pd; }
        }
    }
}

// ---------------------------------------------------------------------------
// Wave-cooperative online-softmax aggregation, 2-edge-parallel float2 gathers.
// First P pair-gathers HOISTED above the softmax shuffle chain so their L3
// latency overlaps it (padded slots re-read cs[beg]'s row -> L1 hit, w=0).
// F lanes per node (F=64: 1 node/wave; F=32: 2 nodes/wave).
// ---------------------------------------------------------------------------
template <int F, int P>
__global__ __launch_bounds__(256) void aggregate(
    const float* __restrict__ h, const float* __restrict__ hs,
    const float* __restrict__ hd, const int* __restrict__ rp,
    const int* __restrict__ cs, const float* __restrict__ b,
    float* __restrict__ out, int n) {
    constexpr int NPW = 64 / F;            // nodes per wave
    constexpr int HF  = F / 2;
    int wid  = (blockIdx.x * blockDim.x + threadIdx.x) >> 6;
    int lane = threadIdx.x & 63;
    int fl   = lane % F;
    int node = wid * NPW + lane / F;
    if (node >= n) return;
    int beg = rp[node], end = rp[node + 1];
    float hdn = hd[node];

    int half = (fl >= HF) ? 1 : 0;         // which edge of each pair
    int f2   = (fl & (HF - 1)) * 2;        // feature-pair base
    float2 bb2 = *reinterpret_cast<const float2*>(&b[f2]);

    float m = -1e30f, s = 0.f;
    float2 acc = make_float2(0.f, 0.f);

    for (int base = beg; base < end; base += F) {
        int e = base + fl;
        bool v = e < end;
        int src = cs[v ? e : beg];

        // hoisted pair gathers (independent of the softmax chain)
        float2 hp[P];
#pragma unroll
        for (int u = 0; u < P; ++u) {
            int se = __shfl(src, 2 * u + half, F);
            hp[u] = *reinterpret_cast<const float2*>(&h[(size_t)se * F + f2]);
        }

        // lane-parallel logits + wave softmax
        float l = hs[src] + hdn;
        l = (l > 0.f) ? l : NEG_SLOPE * l;
        l = v ? l : -1e30f;
        float lm = l;
#pragma unroll
        for (int off = HF; off; off >>= 1)
            lm = fmaxf(lm, __shfl_xor(lm, off, F));
        float mn = fmaxf(m, lm);
        float w = __expf(l - mn);          // exactly 0 for padded lanes
        float ws = w;
#pragma unroll
        for (int off = HF; off; off >>= 1)
            ws += __shfl_xor(ws, off, F);
        float sc = __expf(m - mn);
        s = fmaf(s, sc, ws);
        acc.x *= sc; acc.y *= sc;
        m = mn;

        // consume hoisted pairs (w of padded edges is 0)
#pragma unroll
        for (int u = 0; u < P; ++u) {
            float we = __shfl(w, 2 * u + half, F);
            acc.x = fmaf(we, hp[u].x, acc.x);
            acc.y = fmaf(we, hp[u].y, acc.y);
        }

        // remainder pairs (deg > 2P), batched x4 with predicates
        int cc = min(F, end - base);
        for (int t = P; 2 * t < cc; t += 4) {
            float2 hv[4];
            float  wv[4];
#pragma unroll
            for (int u = 0; u < 4; ++u) {
                int tt = t + u;
                bool pv = (2 * tt < cc);
                int jj = pv ? (2 * tt + half) : 0;
                int   se = __shfl(src, jj, F);
                float we = __shfl(w,   jj, F);
                wv[u] = pv ? we : 0.f;
                hv[u] = *reinterpret_cast<const float2*>(&h[(size_t)se * F + f2]);
            }
#pragma unroll
            for (int u = 0; u < 4; ++u) {
                acc.x = fmaf(wv[u], hv[u].x, acc.x);
                acc.y = fmaf(wv[u], hv[u].y, acc.y);
            }
        }
    }

    // merge the two edge-stream halves (partner lane = same feature pair)
    acc.x += __shfl_xor(acc.x, HF, F);
    acc.y += __shfl_xor(acc.y, HF, F);

    float inv = 1.f / (s + 1e-16f);
    float2 res;
    res.x = fmaxf(fmaf(acc.x, inv, bb2.x), 0.f);
    res.y = fmaxf(fmaf(acc.y, inv, bb2.y), 0.f);
    if (half == 0)
        *reinterpret_cast<float2*>(&out[(size_t)node * F + f2]) = res;
}

// ---------------------------------------------------------------------------
// Global mean pool (batch is sorted): LDS pre-reduction then global atomics
// ---------------------------------------------------------------------------
__global__ void pool_kernel(const float* __restrict__ x, const int* __restrict__ batch,
                            float* __restrict__ pool, float* __restrict__ gcnt, int n) {
    __shared__ float lp[64 * 32];
    __shared__ float lc[64];
    int tid = threadIdx.x;
    for (int i = tid; i < 64 * 32; i += 256) lp[i] = 0.f;
    if (tid < 64) lc[tid] = 0.f;
    __syncthreads();
    int f = tid % 32, r = tid / 32;
    int base = blockIdx.x * 64;
    for (int i = r; i < 64; i += 8) {
        int node = base + i;
        if (node < n) {
            int g = batch[node];
            atomicAdd(&lp[g * 32 + f], x[(size_t)node * 32 + f]);
            if (f == 0) atomicAdd(&lc[g], 1.f);
        }
    }
    __syncthreads();
    for (int i = tid; i < 64 * 32; i += 256)
        if (lp[i] != 0.f) atomicAdd(&pool[i], lp[i]);
    if (tid < 64 && lc[tid] != 0.f) atomicAdd(&gcnt[tid], lc[tid]);
}

__global__ void finalize(const float* __restrict__ pool, const float* __restrict__ gcnt,
                         float* __restrict__ out, int total) {
    int i = blockIdx.x * blockDim.x + threadIdx.x;
    if (i >= total) return;
    out[i] = pool[i] / fmaxf(gcnt[i / 32], 1.f);
}

// ---------------------------------------------------------------------------
extern "C" void kernel_launch(void* const* d_in, const int* in_sizes, int n_in,
                              void* d_out, int out_size, void* d_ws, size_t ws_size,
                              hipStream_t stream) {
    const float* x    = (const float*)d_in[0];
    const int*   ei   = (const int*)d_in[1];
    const int*   batch= (const int*)d_in[2];
    const float* W1   = (const float*)d_in[3];
    const float* as1  = (const float*)d_in[4];
    const float* ad1  = (const float*)d_in[5];
    const float* b1   = (const float*)d_in[6];
    const float* W2   = (const float*)d_in[7];
    const float* as2  = (const float*)d_in[8];
    const float* ad2  = (const float*)d_in[9];
    const float* b2   = (const float*)d_in[10];
    const float* W3   = (const float*)d_in[11];
    const float* as3  = (const float*)d_in[12];
    const float* ad3  = (const float*)d_in[13];
    const float* b3   = (const float*)d_in[14];
    float* out = (float*)d_out;

    const int N  = in_sizes[0] / 128;
    const int E  = in_sizes[1] / 2;
    const int ET = E + N;
    const int G  = 64;
    const int NB = (N + 511) / 512;        // coarse buckets (512 nodes each)

    char* p = (char*)d_ws;
    auto alloc = [&](size_t bytes) {
        char* r = p;
        p += (bytes + 255) & ~(size_t)255;
        return r;
    };
    int*   rp     = (int*)alloc((size_t)(N + 1) * 4);
    int*   bkcnt  = (int*)alloc(1024);
    int*   bbase  = (int*)alloc(1024 + 4);
    int*   bcur   = (int*)alloc(1024);
    int*   cs     = (int*)alloc((size_t)ET * 4);
    float* hA     = (float*)alloc((size_t)N * 64 * 4);   // h1 / h3(Nx32)
    float* hB     = (float*)alloc((size_t)N * 64 * 4);   // h2
    float* xA     = (float*)alloc((size_t)N * 64 * 4);   // act1 / final act3
    float* xB     = (float*)alloc((size_t)N * 64 * 4);   // act2
    float* hs     = (float*)alloc((size_t)N * 4);
    float* hd     = (float*)alloc((size_t)N * 4);
    float* pool   = (float*)alloc((size_t)G * 32 * 4);
    float* gcnt   = (float*)alloc((size_t)G * 4);
    // ebuf (bucket-ordered (src,dst) pairs, ET*8 B) aliases xA: CSR build
    // (local_fill2 = last reader) completes before aggregate-1 writes xA.
    int2*  ebuf   = (int2*)xA;

    // ---- CSR by destination (shared across all 3 layers) ----
    hipMemsetAsync(bkcnt, 0, 1024, stream);
    bucket_count<<<(ET + 2047) / 2048, 256, 0, stream>>>(ei, bkcnt, E, ET);
    bucket_scan<<<1, 256, 0, stream>>>(bkcnt, NB, bbase, bcur, rp, N);
    int bb = (ET + 256 * BIN_K - 1) / (256 * BIN_K);
    bin_edges<<<bb, 256, 0, stream>>>(ei, bcur, ebuf, E, ET);
    local_fill2<<<NB, 256, 0, stream>>>(ebuf, bbase, rp, cs, N);

    int gb   = (N + 63) / 64;
    int ab64 = (N + 3) / 4;        // 4 waves/block, 1 node/wave
    int ab32 = (N + 7) / 8;        // 4 waves/block, 2 nodes/wave

    // ---- layer 1: 128 -> 64 ----
    gemm_attn<128, 64><<<gb, 256, 0, stream>>>(x, W1, as1, ad1, hA, hs, hd, N);
    aggregate<64, 12><<<ab64, 256, 0, stream>>>(hA, hs, hd, rp, cs, b1, xA, N);
    // ---- layer 2: 64 -> 64 ----
    gemm_attn<64, 64><<<gb, 256, 0, stream>>>(xA, W2, as2, ad2, hB, hs, hd, N);
    aggregate<64, 12><<<ab64, 256, 0, stream>>>(hB, hs, hd, rp, cs, b2, xB, N);
    // ---- layer 3: 64 -> 32 ----
    gemm_attn<64, 32><<<gb, 128, 0, stream>>>(xB, W3, as3, ad3, hA, hs, hd, N);
    aggregate<32, 8><<<ab32, 256, 0, stream>>>(hA, hs, hd, rp, cs, b3, xA, N);

    // ---- global mean pool ----
    hipMemsetAsync(pool, 0, (size_t)G * 32 * 4, stream);
    hipMemsetAsync(gcnt, 0, (size_t)G * 4, stream);
    pool_kernel<<<(N + 63) / 64, 256, 0, stream>>>(xA, batch, pool, gcnt, N);
    finalize<<<(G * 32 + 255) / 256, 256, 0, stream>>>(pool, gcnt, out, G * 32);
}

// Round 8
// 326.151 us; speedup vs baseline: 1.3709x; 1.0074x over previous
//
#include <hip/hip_runtime.h>
#include <cstdint>
#include <cstddef>

#define NEG_SLOPE 0.2f

// ---------------------------------------------------------------------------
// CSR build: bucket_count -> bucket_scan (1 block) -> bin_edges -> local_fill2
// (bucket = 512 consecutive dst nodes; per-node rp built inside each bucket)
// ---------------------------------------------------------------------------
__global__ __launch_bounds__(256) void bucket_count(
    const int* __restrict__ ei, int* __restrict__ bkcnt, int E, int total) {
    __shared__ int lh[256];
    int tid = threadIdx.x;
    lh[tid] = 0;
    __syncthreads();
    int i = blockIdx.x * (256 * 8) + tid;
#pragma unroll
    for (int k = 0; k < 8; ++k, i += 256) {
        if (i < total) {
            int dst = (i < E) ? ei[E + i] : (i - E);   // self-loops appended
            atomicAdd(&lh[dst >> 9], 1);
        }
    }
    __syncthreads();
    if (lh[tid]) atomicAdd(&bkcnt[tid], lh[tid]);
}

// 1 block: exclusive scan over nb (<=256) buckets; writes bbase, bcur, rp[n]
__global__ void bucket_scan(const int* __restrict__ bkcnt, int nb,
                            int* __restrict__ bbase, int* __restrict__ bcur,
                            int* __restrict__ rp, int n) {
    __shared__ int sc[256];
    int t = threadIdx.x;
    int v = (t < nb) ? bkcnt[t] : 0;
    sc[t] = v;
    __syncthreads();
    for (int off = 1; off < 256; off <<= 1) {
        int x = (t >= off) ? sc[t - off] : 0;
        __syncthreads();
        sc[t] += x;
        __syncthreads();
    }
    int excl = sc[t] - v;
    if (t < nb) { bbase[t] = excl; bcur[t] = excl; }
    if (t == 255) { bbase[nb] = sc[255]; rp[n] = sc[255]; }
}

// ---------------------------------------------------------------------------
// Pass 1: bin edges into 512-node coarse buckets (per-block LDS histogram,
// one global atomic per touched bucket to reserve a contiguous run).
// ---------------------------------------------------------------------------
#define BIN_K 16   // edges per thread; chunk = 256*16 = 4096
__global__ __launch_bounds__(256) void bin_edges(
    const int* __restrict__ ei, int* __restrict__ bcur,
    int2* __restrict__ ebuf, int E, int total) {
    __shared__ int lhist[256];
    __shared__ int lbase[256];
    int tid = threadIdx.x;
    lhist[tid] = 0;
    __syncthreads();
    int base_e = blockIdx.x * (256 * BIN_K);
    int s[BIN_K], d[BIN_K], bk[BIN_K];
#pragma unroll
    for (int k = 0; k < BIN_K; ++k) {
        int e = base_e + tid + k * 256;
        bool v = e < total;
        int ee = v ? e : 0;
        if (ee < E) { s[k] = ei[ee]; d[k] = ei[E + ee]; }
        else        { s[k] = d[k] = ee - E; }
        bk[k] = v ? (d[k] >> 9) : -1;
        if (v) atomicAdd(&lhist[bk[k]], 1);
    }
    __syncthreads();
    int h = lhist[tid];
    lbase[tid] = (h > 0) ? atomicAdd(&bcur[tid], h) : 0;
    __syncthreads();
    lhist[tid] = 0;
    __syncthreads();
#pragma unroll
    for (int k = 0; k < BIN_K; ++k) {
        if (bk[k] >= 0) {
            int r = atomicAdd(&lhist[bk[k]], 1);
            ebuf[(size_t)lbase[bk[k]] + r] = make_int2(s[k], d[k]);
        }
    }
}

// ---------------------------------------------------------------------------
// Pass 2: one block per bucket. Builds per-node rp (LDS histogram + scan of
// the bucket's 512 nodes) and places edges with LDS cursors. All cs writes
// confined to the bucket's window -> lines filled by one XCD.
// ---------------------------------------------------------------------------
__global__ __launch_bounds__(256) void local_fill2(
    const int2* __restrict__ ebuf, const int* __restrict__ bbase,
    int* __restrict__ rp, int* __restrict__ cs, int n) {
    __shared__ int lhist[512];
    __shared__ int lscan[256];
    __shared__ int lcur[512];
    int b = blockIdx.x;
    int node0 = b * 512;
    int nodes = min(512, n - node0);
    int tid = threadIdx.x;
    int beg = bbase[b], end = bbase[b + 1];

    lhist[tid] = 0; lhist[tid + 256] = 0;
    __syncthreads();

    // pass A: histogram by node (batched x4)
    for (int i0 = beg; i0 < end; i0 += 256 * 4) {
        int2 pr[4]; int idx[4];
#pragma unroll
        for (int u = 0; u < 4; ++u) {
            idx[u] = i0 + tid + u * 256;
            pr[u] = ebuf[(idx[u] < end) ? idx[u] : beg];
        }
#pragma unroll
        for (int u = 0; u < 4; ++u)
            if (idx[u] < end) atomicAdd(&lhist[pr[u].y - node0], 1);
    }
    __syncthreads();

    // scan 512 elements (2 per thread)
    int a0 = lhist[2 * tid], a1 = lhist[2 * tid + 1];
    int psum = a0 + a1;
    lscan[tid] = psum;
    __syncthreads();
    for (int off = 1; off < 256; off <<= 1) {
        int x = (tid >= off) ? lscan[tid - off] : 0;
        __syncthreads();
        lscan[tid] += x;
        __syncthreads();
    }
    int e0 = beg + (lscan[tid] - psum);    // node 2*tid first-edge position
    int e1 = e0 + a0;                      // node 2*tid+1 first-edge position
    if (2 * tid < nodes)     rp[node0 + 2 * tid]     = e0;
    if (2 * tid + 1 < nodes) rp[node0 + 2 * tid + 1] = e1;
    lcur[2 * tid] = e0;
    lcur[2 * tid + 1] = e1;
    __syncthreads();

    // pass B: place edges (batched x4)
    for (int i0 = beg; i0 < end; i0 += 256 * 4) {
        int2 pr[4]; int idx[4];
#pragma unroll
        for (int u = 0; u < 4; ++u) {
            idx[u] = i0 + tid + u * 256;
            pr[u] = ebuf[(idx[u] < end) ? idx[u] : beg];
        }
#pragma unroll
        for (int u = 0; u < 4; ++u) {
            if (idx[u] < end) {
                int pos = atomicAdd(&lcur[pr[u].y - node0], 1);
                cs[pos] = pr[u].x;
            }
        }
    }
}

// ---------------------------------------------------------------------------
// Fused projection + attention dots:  h = x @ W ; hs = h@a_s ; hd = h@a_d
// Register blocking: 4 nodes x 4 features per thread; W staged in LDS.
// ---------------------------------------------------------------------------
template <int INF, int OUTF>
__global__ void gemm_attn(const float* __restrict__ x, const float* __restrict__ W,
                          const float* __restrict__ a_s, const float* __restrict__ a_d,
                          float* __restrict__ h, float* __restrict__ hs,
                          float* __restrict__ hd, int n) {
    constexpr int FC  = OUTF / 4;          // threads along feature dim
    constexpr int NPB = 64;                // nodes per block
    constexpr int NT  = FC * (NPB / 4);    // threads per block
    __shared__ float Wl[INF * OUTF];
    int tid = threadIdx.x;
    for (int i = tid; i < INF * OUTF; i += NT) Wl[i] = W[i];
    __syncthreads();

    int fc = tid % FC;
    int nc = tid / FC;                     // 0..15
    int n0 = blockIdx.x * NPB + nc * 4;
    int ni[4];
#pragma unroll
    for (int i = 0; i < 4; ++i) { int v = n0 + i; ni[i] = (v < n) ? v : (n - 1); }

    float acc[4][4] = {};
#pragma unroll 2
    for (int k = 0; k < INF; k += 4) {
        float4 xv[4];
#pragma unroll
        for (int i = 0; i < 4; ++i)
            xv[i] = *reinterpret_cast<const float4*>(&x[(size_t)ni[i] * INF + k]);
#pragma unroll
        for (int j = 0; j < 4; ++j) {
            float4 wv = *reinterpret_cast<const float4*>(&Wl[(k + j) * OUTF + fc * 4]);
#pragma unroll
            for (int i = 0; i < 4; ++i) {
                float xs = (&xv[i].x)[j];
                acc[i][0] = fmaf(xs, wv.x, acc[i][0]);
                acc[i][1] = fmaf(xs, wv.y, acc[i][1]);
                acc[i][2] = fmaf(xs, wv.z, acc[i][2]);
                acc[i][3] = fmaf(xs, wv.w, acc[i][3]);
            }
        }
    }

    float asv[4], adv[4];
#pragma unroll
    for (int j = 0; j < 4; ++j) { asv[j] = a_s[fc * 4 + j]; adv[j] = a_d[fc * 4 + j]; }

#pragma unroll
    for (int i = 0; i < 4; ++i) {
        float ps = acc[i][0] * asv[0] + acc[i][1] * asv[1] +
                   acc[i][2] * asv[2] + acc[i][3] * asv[3];
        float pd = acc[i][0] * adv[0] + acc[i][1] * adv[1] +
                   acc[i][2] * adv[2] + acc[i][3] * adv[3];
#pragma unroll
        for (int off = FC >> 1; off; off >>= 1) {
            ps += __shfl_xor(ps, off, FC);
            pd += __shfl_xor(pd, off, FC);
        }
        int node = n0 + i;
        if (node < n) {
            *reinterpret_cast<float4*>(&h[(size_t)node * OUTF + fc * 4]) =
                make_float4(acc[i][0], acc[i][1], acc[i][2], acc[i][3]);
            if (fc == 0) { hs[node] = ps; hd[node] = pd; }
        }
    }
}

// ---------------------------------------------------------------------------
// Wave-cooperative online-softmax aggregation, 4-edge-parallel float4 gathers.
// F lanes per node (F=64: 1 node/wave; F=32: 2 nodes/wave). Lanes split into
// 4 groups of F/4; group g handles edge 4t+g; each lane covers a feature QUAD
// via one dwordx4 gather (one group = one full h row). First P4 quad-gathers
// hoisted above the softmax shuffle chain (L3 latency overlaps it).
// Final merge: shfl_xor(F/4) + shfl_xor(F/2) sum the 4 edge streams.
// ---------------------------------------------------------------------------
template <int F, int P4>
__global__ __launch_bounds__(256) void aggregate(
    const float* __restrict__ h, const float* __restrict__ hs,
    const float* __restrict__ hd, const int* __restrict__ rp,
    const int* __restrict__ cs, const float* __restrict__ b,
    float* __restrict__ out, int n) {
    constexpr int NPW = 64 / F;            // nodes per wave
    constexpr int HF  = F / 2;
    constexpr int QF  = F / 4;             // lanes per group
    int wid  = (blockIdx.x * blockDim.x + threadIdx.x) >> 6;
    int lane = threadIdx.x & 63;
    int fl   = lane % F;
    int node = wid * NPW + lane / F;
    if (node >= n) return;
    int beg = rp[node], end = rp[node + 1];
    float hdn = hd[node];

    int grp = fl / QF;                     // 0..3: which edge of each quad
    int f4  = (fl % QF) * 4;               // feature-quad base
    float4 bb4 = *reinterpret_cast<const float4*>(&b[f4]);

    float m = -1e30f, s = 0.f;
    float4 acc = make_float4(0.f, 0.f, 0.f, 0.f);

    for (int base = beg; base < end; base += F) {
        int e = base + fl;
        bool v = e < end;
        int src = cs[v ? e : beg];

        // hoisted quad gathers (independent of the softmax chain)
        float4 hq[P4];
#pragma unroll
        for (int u = 0; u < P4; ++u) {
            int se = __shfl(src, 4 * u + grp, F);
            hq[u] = *reinterpret_cast<const float4*>(&h[(size_t)se * F + f4]);
        }

        // lane-parallel logits + wave softmax
        float l = hs[src] + hdn;
        l = (l > 0.f) ? l : NEG_SLOPE * l;
        l = v ? l : -1e30f;
        float lm = l;
#pragma unroll
        for (int off = HF; off; off >>= 1)
            lm = fmaxf(lm, __shfl_xor(lm, off, F));
        float mn = fmaxf(m, lm);
        float w = __expf(l - mn);          // exactly 0 for padded lanes
        float ws = w;
#pragma unroll
        for (int off = HF; off; off >>= 1)
            ws += __shfl_xor(ws, off, F);
        float sc = __expf(m - mn);
        s = fmaf(s, sc, ws);
        acc.x *= sc; acc.y *= sc; acc.z *= sc; acc.w *= sc;
        m = mn;

        // consume hoisted quads (w of padded/out-of-range edges is 0)
#pragma unroll
        for (int u = 0; u < P4; ++u) {
            float we = __shfl(w, 4 * u + grp, F);
            acc.x = fmaf(we, hq[u].x, acc.x);
            acc.y = fmaf(we, hq[u].y, acc.y);
            acc.z = fmaf(we, hq[u].z, acc.z);
            acc.w = fmaf(we, hq[u].w, acc.w);
        }

        // remainder quads (deg > 4*P4), batched x2 with predicates
        int cc = min(F, end - base);
        for (int t = P4; 4 * t < cc; t += 2) {
            float4 hv[2];
            float  wv[2];
#pragma unroll
            for (int u = 0; u < 2; ++u) {
                int tt = t + u;
                bool pv = (4 * tt < cc);
                int jj = pv ? (4 * tt + grp) : 0;   // < F by construction
                int   se = __shfl(src, jj, F);
                float we = __shfl(w,   jj, F);
                wv[u] = pv ? we : 0.f;
                hv[u] = *reinterpret_cast<const float4*>(&h[(size_t)se * F + f4]);
            }
#pragma unroll
            for (int u = 0; u < 2; ++u) {
                acc.x = fmaf(wv[u], hv[u].x, acc.x);
                acc.y = fmaf(wv[u], hv[u].y, acc.y);
                acc.z = fmaf(wv[u], hv[u].z, acc.z);
                acc.w = fmaf(wv[u], hv[u].w, acc.w);
            }
        }
    }

    // merge the 4 edge-stream groups (xor QF flips grp bit0, xor 2QF bit1)
    acc.x += __shfl_xor(acc.x, QF, F);
    acc.y += __shfl_xor(acc.y, QF, F);
    acc.z += __shfl_xor(acc.z, QF, F);
    acc.w += __shfl_xor(acc.w, QF, F);
    acc.x += __shfl_xor(acc.x, 2 * QF, F);
    acc.y += __shfl_xor(acc.y, 2 * QF, F);
    acc.z += __shfl_xor(acc.z, 2 * QF, F);
    acc.w += __shfl_xor(acc.w, 2 * QF, F);

    float inv = 1.f / (s + 1e-16f);
    float4 res;
    res.x = fmaxf(fmaf(acc.x, inv, bb4.x), 0.f);
    res.y = fmaxf(fmaf(acc.y, inv, bb4.y), 0.f);
    res.z = fmaxf(fmaf(acc.z, inv, bb4.z), 0.f);
    res.w = fmaxf(fmaf(acc.w, inv, bb4.w), 0.f);
    if (grp == 0)
        *reinterpret_cast<float4*>(&out[(size_t)node * F + f4]) = res;
}

// ---------------------------------------------------------------------------
// Global mean pool (batch is sorted): LDS pre-reduction then global atomics
// ---------------------------------------------------------------------------
__global__ void pool_kernel(const float* __restrict__ x, const int* __restrict__ batch,
                            float* __restrict__ pool, float* __restrict__ gcnt, int n) {
    __shared__ float lp[64 * 32];
    __shared__ float lc[64];
    int tid = threadIdx.x;
    for (int i = tid; i < 64 * 32; i += 256) lp[i] = 0.f;
    if (tid < 64) lc[tid] = 0.f;
    __syncthreads();
    int f = tid % 32, r = tid / 32;
    int base = blockIdx.x * 64;
    for (int i = r; i < 64; i += 8) {
        int node = base + i;
        if (node < n) {
            int g = batch[node];
            atomicAdd(&lp[g * 32 + f], x[(size_t)node * 32 + f]);
            if (f == 0) atomicAdd(&lc[g], 1.f);
        }
    }
    __syncthreads();
    for (int i = tid; i < 64 * 32; i += 256)
        if (lp[i] != 0.f) atomicAdd(&pool[i], lp[i]);
    if (tid < 64 && lc[tid] != 0.f) atomicAdd(&gcnt[tid], lc[tid]);
}

__global__ void finalize(const float* __restrict__ pool, const float* __restrict__ gcnt,
                         float* __restrict__ out, int total) {
    int i = blockIdx.x * blockDim.x + threadIdx.x;
    if (i >= total) return;
    out[i] = pool[i] / fmaxf(gcnt[i / 32], 1.f);
}

// ---------------------------------------------------------------------------
extern "C" void kernel_launch(void* const* d_in, const int* in_sizes, int n_in,
                              void* d_out, int out_size, void* d_ws, size_t ws_size,
                              hipStream_t stream) {
    const float* x    = (const float*)d_in[0];
    const int*   ei   = (const int*)d_in[1];
    const int*   batch= (const int*)d_in[2];
    const float* W1   = (const float*)d_in[3];
    const float* as1  = (const float*)d_in[4];
    const float* ad1  = (const float*)d_in[5];
    const float* b1   = (const float*)d_in[6];
    const float* W2   = (const float*)d_in[7];
    const float* as2  = (const float*)d_in[8];
    const float* ad2  = (const float*)d_in[9];
    const float* b2   = (const float*)d_in[10];
    const float* W3   = (const float*)d_in[11];
    const float* as3  = (const float*)d_in[12];
    const float* ad3  = (const float*)d_in[13];
    const float* b3   = (const float*)d_in[14];
    float* out = (float*)d_out;

    const int N  = in_sizes[0] / 128;
    const int E  = in_sizes[1] / 2;
    const int ET = E + N;
    const int G  = 64;
    const int NB = (N + 511) / 512;        // coarse buckets (512 nodes each)

    char* p = (char*)d_ws;
    auto alloc = [&](size_t bytes) {
        char* r = p;
        p += (bytes + 255) & ~(size_t)255;
        return r;
    };
    int*   rp     = (int*)alloc((size_t)(N + 1) * 4);
    int*   bkcnt  = (int*)alloc(1024);
    int*   bbase  = (int*)alloc(1024 + 4);
    int*   bcur   = (int*)alloc(1024);
    int*   cs     = (int*)alloc((size_t)ET * 4);
    float* hA     = (float*)alloc((size_t)N * 64 * 4);   // h1 / h3(Nx32)
    float* hB     = (float*)alloc((size_t)N * 64 * 4);   // h2
    float* xA     = (float*)alloc((size_t)N * 64 * 4);   // act1 / final act3
    float* xB     = (float*)alloc((size_t)N * 64 * 4);   // act2
    float* hs     = (float*)alloc((size_t)N * 4);
    float* hd     = (float*)alloc((size_t)N * 4);
    float* pool   = (float*)alloc((size_t)G * 32 * 4);
    float* gcnt   = (float*)alloc((size_t)G * 4);
    // ebuf (bucket-ordered (src,dst) pairs, ET*8 B) aliases xA: CSR build
    // (local_fill2 = last reader) completes before aggregate-1 writes xA.
    int2*  ebuf   = (int2*)xA;

    // ---- CSR by destination (shared across all 3 layers) ----
    hipMemsetAsync(bkcnt, 0, 1024, stream);
    bucket_count<<<(ET + 2047) / 2048, 256, 0, stream>>>(ei, bkcnt, E, ET);
    bucket_scan<<<1, 256, 0, stream>>>(bkcnt, NB, bbase, bcur, rp, N);
    int bb = (ET + 256 * BIN_K - 1) / (256 * BIN_K);
    bin_edges<<<bb, 256, 0, stream>>>(ei, bcur, ebuf, E, ET);
    local_fill2<<<NB, 256, 0, stream>>>(ebuf, bbase, rp, cs, N);

    int gb   = (N + 63) / 64;
    int ab64 = (N + 3) / 4;        // 4 waves/block, 1 node/wave
    int ab32 = (N + 7) / 8;        // 4 waves/block, 2 nodes/wave

    // ---- layer 1: 128 -> 64 ----
    gemm_attn<128, 64><<<gb, 256, 0, stream>>>(x, W1, as1, ad1, hA, hs, hd, N);
    aggregate<64, 6><<<ab64, 256, 0, stream>>>(hA, hs, hd, rp, cs, b1, xA, N);
    // ---- layer 2: 64 -> 64 ----
    gemm_attn<64, 64><<<gb, 256, 0, stream>>>(xA, W2, as2, ad2, hB, hs, hd, N);
    aggregate<64, 6><<<ab64, 256, 0, stream>>>(hB, hs, hd, rp, cs, b2, xB, N);
    // ---- layer 3: 64 -> 32 ----
    gemm_attn<64, 32><<<gb, 128, 0, stream>>>(xB, W3, as3, ad3, hA, hs, hd, N);
    aggregate<32, 6><<<ab32, 256, 0, stream>>>(hA, hs, hd, rp, cs, b3, xA, N);

    // ---- global mean pool ----
    hipMemsetAsync(pool, 0, (size_t)G * 32 * 4, stream);
    hipMemsetAsync(gcnt, 0, (size_t)G * 4, stream);
    pool_kernel<<<(N + 63) / 64, 256, 0, stream>>>(xA, batch, pool, gcnt, N);
    finalize<<<(G * 32 + 255) / 256, 256, 0, stream>>>(pool, gcnt, out, G * 32);
}